// Round 6
// baseline (190.346 us; speedup 1.0000x reference)
//
#include <hip/hip_runtime.h>
#include <hip/hip_bf16.h>

typedef __bf16 bf16_t;
typedef __bf16 bf16x8 __attribute__((ext_vector_type(8)));
typedef float  f32x4  __attribute__((ext_vector_type(4)));

#define B_ 8
#define T_ 2048
#define C_ 1024
#define H_ 64

#define MFMA16(a, b, c) __builtin_amdgcn_mfma_f32_16x16x32_bf16((a), (b), (c), 0, 0, 0)
// async global->LDS, 16B per lane; dest = wave-uniform base + lane*16 (linear)
#define GLL16(g, l) __builtin_amdgcn_global_load_lds( \
    (const __attribute__((address_space(1))) unsigned int*)(g), \
    (__attribute__((address_space(3))) unsigned int*)(l), 16, 0, 0)

// ---------------------------------------------------------------------------
// Kernel 1: W fp32 -> concatenated hi/lo bf16 [192][1024] (q|k|v rows).
// ---------------------------------------------------------------------------
__global__ __launch_bounds__(256) void wconv_kernel(
    const float* __restrict__ Wk, const float* __restrict__ Wq,
    const float* __restrict__ Wv,
    bf16_t* __restrict__ Wh, bf16_t* __restrict__ Wl)
{
    int i = blockIdx.x * 256 + threadIdx.x;
    int r = i >> 10;
    int c = i & 1023;
    float v;
    if (r < 64)       v = Wq[r * 1024 + c];
    else if (r < 128) v = Wk[(r - 64) * 1024 + c];
    else              v = Wv[(r - 128) * 1024 + c];
    bf16_t h = (bf16_t)v;
    Wh[i] = h;
    Wl[i] = (bf16_t)(v - (float)h);
}

// ---------------------------------------------------------------------------
// Kernel 2: QKV projection (R5: GLL staging + lane-linear LDS).
// 512 blocks x 256 threads, 2 blocks/CU.  Per K-step(32) the W tile is 24
// lane-linear 1KB fragment groups [mat(2) x nt(12)]: group g holds rows
// nt*16..+15, k-part quad, element addr = lane*16B.  Staged via
// global_load_lds (6 calls/wave, no dest VGPRs), double-buffered, counted
// vmcnt(6), two barriers/iter (R4-attn proven pattern).  Both the GLL writes
// and ds_read_b128 fragment reads are conflict-free (old 80B-stride layout
// was ~4-way conflicted: 6.29M SQ_LDS_BANK_CONFLICT).  x stays in registers
// (2-deep prefetch), issued BEFORE the GLLs so compiler x-waits don't drain
// the staging queue.
// ---------------------------------------------------------------------------
__global__ __launch_bounds__(256, 2) void proj_kernel(
    const float*  __restrict__ x,
    const bf16_t* __restrict__ Wh, const bf16_t* __restrict__ Wl,
    bf16_t* __restrict__ qh, bf16_t* __restrict__ ql,
    bf16_t* __restrict__ kh, bf16_t* __restrict__ kl,
    bf16_t* __restrict__ vh)
{
    __shared__ bf16_t Wlds[2][24][512];    // 48 KB, double-buffered

    const int tid   = threadIdx.x;
    const int wid   = tid >> 6;
    const int lane  = tid & 63;
    const int quad  = lane >> 4;
    const int l16   = lane & 15;
    const int mhalf = wid >> 1;            // which 16-row group
    const int nhalf = wid & 1;             // which 96-col group
    const int g     = blockIdx.x * 32 + mhalf * 16 + l16;
    const float* xrow = x + (size_t)g * C_;

    // staging: wave w fills groups 6w..6w+5; per-lane source offset
    auto stage = [&](int k0, int bufi) {
        #pragma unroll
        for (int i = 0; i < 6; ++i) {
            int grp = wid * 6 + i;
            int mat = (grp >= 12);
            int nt  = mat ? grp - 12 : grp;
            const bf16_t* src = (mat ? Wl : Wh) + (nt * 16 + l16) * 1024 + k0 + quad * 8;
            GLL16(src, &Wlds[bufi][grp][0]);
        }
    };

    f32x4 x0a, x0b, x1a, x1b;
    x0a = *(const f32x4*)(xrow + quad * 8);
    x0b = *(const f32x4*)(xrow + quad * 8 + 4);
    x1a = *(const f32x4*)(xrow + 32 + quad * 8);
    x1b = *(const f32x4*)(xrow + 32 + quad * 8 + 4);
    stage(0, 0);

    f32x4 acc[6];
    #pragma unroll
    for (int i = 0; i < 6; ++i) acc[i] = (f32x4){0.f, 0.f, 0.f, 0.f};

    int buf = 0;
    for (int it = 0; it < 32; ++it) {
        // x shift + prefetch (issued before GLLs)
        float xv[8];
        *(f32x4*)xv       = x0a;
        *(f32x4*)(xv + 4) = x0b;
        x0a = x1a; x0b = x1b;
        if (it + 2 < 32) {
            x1a = *(const f32x4*)(xrow + (it + 2) * 32 + quad * 8);
            x1b = *(const f32x4*)(xrow + (it + 2) * 32 + quad * 8 + 4);
        }

        // stage next K-tile into buf^1; keep its 6 GLLs in flight
        if (it + 1 < 32) {
            stage((it + 1) * 32, buf ^ 1);
            asm volatile("s_waitcnt vmcnt(6)" ::: "memory");
        } else {
            asm volatile("s_waitcnt vmcnt(0)" ::: "memory");
        }
        __syncthreads();                   // all waves' staging of buf landed

        bf16x8 ah, al;
        #pragma unroll
        for (int jj = 0; jj < 8; ++jj) {
            bf16_t h = (bf16_t)xv[jj];
            ah[jj] = h;
            al[jj] = (bf16_t)(xv[jj] - (float)h);
        }

        #pragma unroll
        for (int nt = 0; nt < 6; ++nt) {
            int grp = nhalf * 6 + nt;
            bf16x8 bh = *(const bf16x8*)(&Wlds[buf][grp][lane * 8]);
            bf16x8 bl = *(const bf16x8*)(&Wlds[buf][12 + grp][lane * 8]);
            acc[nt] = MFMA16(ah, bh, acc[nt]);
            acc[nt] = MFMA16(ah, bl, acc[nt]);
            acc[nt] = MFMA16(al, bh, acc[nt]);
        }

        __syncthreads();                   // done reading buf before re-stage
        buf ^= 1;
    }

    // epilogue: D layout col=lane&15, row=quad*4+reg
    const int rowbase = blockIdx.x * 32 + mhalf * 16 + quad * 4;
    for (int nt = 0; nt < 6; ++nt) {
        int n = (nhalf * 6 + nt) * 16 + l16;
        for (int rr = 0; rr < 4; ++rr) {
            int grow = rowbase + rr;
            int bb = grow >> 11, t = grow & 2047;
            float v  = acc[nt][rr];
            bf16_t h = (bf16_t)v;
            if (n < 64) {
                int off = (bb * T_ + t) * H_ + n;
                qh[off] = h; ql[off] = (bf16_t)(v - (float)h);
            } else if (n < 128) {
                int off = (bb * T_ + t) * H_ + (n - 64);
                kh[off] = h; kl[off] = (bf16_t)(v - (float)h);
            } else {
                vh[(bb * H_ + (n - 128)) * T_ + t] = h;
            }
        }
    }
}

// ---------------------------------------------------------------------------
// Kernel 3: attention (unchanged R4: block-cooperative LDS staging).
// ---------------------------------------------------------------------------
__global__ __launch_bounds__(512, 4) void attn_kernel(
    const bf16_t* __restrict__ qh, const bf16_t* __restrict__ ql,
    const bf16_t* __restrict__ kh, const bf16_t* __restrict__ kl,
    const bf16_t* __restrict__ vh,
    float* __restrict__ Oacc, float* __restrict__ lacc)
{
    __shared__ bf16_t KV[2][3][4096];     // [dbuf][kh|kl|v][64x64] = 48 KB
    __shared__ bf16_t Plds[8][16 * 72];   // per-wave P buffer, 18 KB

    const int tid  = threadIdx.x;
    const int wid  = tid >> 6;
    const int lane = tid & 63;
    const int quad = lane >> 4;
    const int l16  = lane & 15;

    const int b  = blockIdx.x & 7;         // XCD-aligned batch
    const int gp = (blockIdx.x >> 3) & 7;  // pair index
    const int s  = blockIdx.x >> 6;        // j-slice 0..7
    const int gA = gp, gB = 15 - gp;
    const int nA = 2 * gA + 2;             // j-steps of tile A (tile B: 34-nA)

    const int t_nt   = wid >> 1;
    const int t_kk   = wid & 1;
    const int t_l16  = tid & 15;
    const int t_quad = (tid >> 4) & 3;
    const int koff   = (t_nt * 16 + t_l16) * H_ + t_kk * 32 + t_quad * 8;
    const int voff   = (t_nt * 16 + t_l16) * T_ + t_kk * 32 + t_quad * 8;

    auto stage = [&](int j, int bufi) {
        const size_t kbase = (size_t)(b * T_ + 64 * j) * H_;
        GLL16(kh + kbase + koff, &KV[bufi][0][wid * 512]);
        GLL16(kl + kbase + koff, &KV[bufi][1][wid * 512]);
        GLL16(vh + (size_t)b * H_ * T_ + 64 * j + voff, &KV[bufi][2][wid * 512]);
    };

    f32x4  O[4];
    float  rowsum[4];
    bf16x8 aqh[2], aql[2];
    int    gcur = -1;

    auto flushO = [&]() {
        #pragma unroll
        for (int rr = 0; rr < 4; ++rr) {
            int trow = b * T_ + 128 * gcur + 16 * wid + quad * 4 + rr;
            #pragma unroll
            for (int ht = 0; ht < 4; ++ht)
                atomicAdd(Oacc + (size_t)trow * H_ + ht * 16 + l16, O[ht][rr]);
            float s_ = rowsum[rr];
            s_ += __shfl_xor(s_, 1, 64);
            s_ += __shfl_xor(s_, 2, 64);
            s_ += __shfl_xor(s_, 4, 64);
            s_ += __shfl_xor(s_, 8, 64);
            if (l16 == 0) atomicAdd(lacc + trow, s_);
        }
    };

    {
        int u0 = s;
        int j0 = (u0 < nA) ? u0 : (u0 - nA);
        stage(j0, 0);
    }

    int buf = 0;
    for (int u = s; u < 34; u += 8) {
        const int g = (u < nA) ? gA : gB;
        const int j = (u < nA) ? u : (u - nA);

        const int un = u + 8;
        if (un < 34) {
            int jn = (un < nA) ? un : (un - nA);
            stage(jn, buf ^ 1);
            asm volatile("s_waitcnt vmcnt(3)" ::: "memory");
        } else {
            asm volatile("s_waitcnt vmcnt(0)" ::: "memory");
        }
        __syncthreads();

        if (g != gcur) {
            if (gcur >= 0) flushO();
            gcur = g;
            const size_t qoff = (size_t)(b * T_ + 128 * g + 16 * wid + l16) * H_;
            #pragma unroll
            for (int kk = 0; kk < 2; ++kk) {
                aqh[kk] = *(const bf16x8*)(qh + qoff + kk * 32 + quad * 8);
                aql[kk] = *(const bf16x8*)(ql + qoff + kk * 32 + quad * 8);
            }
            #pragma unroll
            for (int i = 0; i < 4; ++i) { O[i] = (f32x4){0.f,0.f,0.f,0.f}; rowsum[i] = 0.f; }
        }

        const bf16_t* Kh = KV[buf][0];
        const bf16_t* Kl = KV[buf][1];
        f32x4 S[4];
        #pragma unroll
        for (int i = 0; i < 4; ++i) S[i] = (f32x4){0.f,0.f,0.f,0.f};
        #pragma unroll
        for (int nt = 0; nt < 4; ++nt) {
            #pragma unroll
            for (int kk = 0; kk < 2; ++kk) {
                bf16x8 bh = *(const bf16x8*)(Kh + (nt * 2 + kk) * 512 + lane * 8);
                bf16x8 bl = *(const bf16x8*)(Kl + (nt * 2 + kk) * 512 + lane * 8);
                S[nt] = MFMA16(aqh[kk], bh, S[nt]);
                S[nt] = MFMA16(aqh[kk], bl, S[nt]);
                S[nt] = MFMA16(aql[kk], bh, S[nt]);
            }
        }

        bf16_t* Pw = Plds[wid];
        const int rloc = 128 * g + 16 * wid + quad * 4;
        #pragma unroll
        for (int nt = 0; nt < 4; ++nt) {
            int colt = 64 * j + nt * 16 + l16;
            #pragma unroll
            for (int rr = 0; rr < 4; ++rr) {
                float pv = (colt <= rloc + rr)
                         ? __expf(fmaf(S[nt][rr], 0.125f, -20.0f)) : 0.f;
                rowsum[rr] += pv;
                Pw[(quad * 4 + rr) * 72 + nt * 16 + l16] = (bf16_t)pv;
            }
        }

        bf16x8 ap0 = *(const bf16x8*)(Pw + l16 * 72 + quad * 8);
        bf16x8 ap1 = *(const bf16x8*)(Pw + l16 * 72 + 32 + quad * 8);

        const bf16_t* Vt = KV[buf][2];
        #pragma unroll
        for (int ht = 0; ht < 4; ++ht) {
            bf16x8 bv0 = *(const bf16x8*)(Vt + (ht * 2 + 0) * 512 + lane * 8);
            bf16x8 bv1 = *(const bf16x8*)(Vt + (ht * 2 + 1) * 512 + lane * 8);
            O[ht] = MFMA16(ap0, bv0, O[ht]);
            O[ht] = MFMA16(ap1, bv1, O[ht]);
        }

        __syncthreads();
        buf ^= 1;
    }
    if (gcur >= 0) flushO();
}

// ---------------------------------------------------------------------------
// Kernel 4: out = Oacc / lacc
// ---------------------------------------------------------------------------
__global__ __launch_bounds__(256) void div_kernel(
    const float* __restrict__ Oacc, const float* __restrict__ lacc,
    float* __restrict__ out)
{
    int i = blockIdx.x * 256 + threadIdx.x;          // f32x4 index, 262144 total
    f32x4 o   = ((const f32x4*)Oacc)[i];
    float inv = 1.0f / lacc[i >> 4];
    ((f32x4*)out)[i] = o * inv;
}

// ---------------------------------------------------------------------------
extern "C" void kernel_launch(void* const* d_in, const int* in_sizes, int n_in,
                              void* d_out, int out_size, void* d_ws, size_t ws_size,
                              hipStream_t stream)
{
    const float* x  = (const float*)d_in[0];
    const float* Wk = (const float*)d_in[1];
    const float* Wq = (const float*)d_in[2];
    const float* Wv = (const float*)d_in[3];
    float* out = (float*)d_out;

    char* ws = (char*)d_ws;
    const size_t WSZ = 192 * 1024 * sizeof(bf16_t);            // 393216
    const size_t QSZ = (size_t)B_ * T_ * H_ * sizeof(bf16_t);  // 2097152
    bf16_t* Wh   = (bf16_t*)(ws);
    bf16_t* Wl   = (bf16_t*)(ws + WSZ);
    bf16_t* qh   = (bf16_t*)(ws + 2 * WSZ);
    bf16_t* ql   = (bf16_t*)(ws + 2 * WSZ + 1 * QSZ);
    bf16_t* kh   = (bf16_t*)(ws + 2 * WSZ + 2 * QSZ);
    bf16_t* kl   = (bf16_t*)(ws + 2 * WSZ + 3 * QSZ);
    bf16_t* vh   = (bf16_t*)(ws + 2 * WSZ + 4 * QSZ);
    float*  Oacc = (float*)(ws + 2 * WSZ + 5 * QSZ);           // 4 MB
    float*  lacc = (float*)(ws + 2 * WSZ + 5 * QSZ + (size_t)B_ * T_ * H_ * 4);

    // zero Oacc (4 MB) + lacc (64 KB), contiguous
    hipMemsetAsync(Oacc, 0, (size_t)B_ * T_ * H_ * 4 + (size_t)B_ * T_ * 4, stream);
    hipLaunchKernelGGL(wconv_kernel, dim3(768), dim3(256), 0, stream, Wk, Wq, Wv, Wh, Wl);
    hipLaunchKernelGGL(proj_kernel, dim3(512), dim3(256), 0, stream,
                       x, Wh, Wl, qh, ql, kh, kl, vh);
    hipLaunchKernelGGL(attn_kernel, dim3(512), dim3(512), 0, stream,
                       qh, ql, kh, kl, vh, Oacc, lacc);
    hipLaunchKernelGGL(div_kernel, dim3(1024), dim3(256), 0, stream, Oacc, lacc, out);
}